// Round 19
// baseline (1362.287 us; speedup 1.0000x reference)
//
#include <hip/hip_runtime.h>
#include <hip/hip_bf16.h>

#define NB   32
#define SEQ  512
#define HID  768
#define FFN  3072
#define NEXP 8

typedef float f32x4 __attribute__((ext_vector_type(4)));
typedef short s16x8 __attribute__((ext_vector_type(8)));

__device__ __forceinline__ unsigned short f2bf(float f) {
    return __builtin_bit_cast(unsigned short, (__bf16)f);
}

__device__ __forceinline__ float fast_exp2(float x) {
    float r; asm("v_exp_f32 %0, %1" : "=v"(r) : "v"(x)); return r;
}
__device__ __forceinline__ float fast_rcp(float x) {
    float r; asm("v_rcp_f32 %0, %1" : "=v"(r) : "v"(x)); return r;
}

// tanh-gelu, overflow-free (exp2 arg <= 0). |error| vs exact-erf gelu ~2e-4.
__device__ __forceinline__ float gelu_fast(float v) {
    float u  = v * (0.7978845608f + 0.0356774081f * v * v);
    float t  = fast_exp2(-2.8853900817779268f * fabsf(u));
    float T  = (1.0f - t) * fast_rcp(1.0f + t);
    return 0.5f * v + 0.5f * fabsf(v) * T;
}

#define GLOAD16(gp, lp) __builtin_amdgcn_global_load_lds( \
    (const __attribute__((address_space(1))) unsigned int*)(gp), \
    (__attribute__((address_space(3))) unsigned int*)(lp), 16, 0, 0)

#define VMCNT(N) asm volatile("s_waitcnt vmcnt(%0)" :: "i"(N) : "memory")

// ---------------------------------------------------------------------------
// Merged prep (single launch): block 0 = label sort; 1..2048 = X fp32->bf16;
// 2049..6656 = W1 transpose; 6657..11264 = W2 transpose. All plain layouts.
// ---------------------------------------------------------------------------
__device__ __forceinline__ void transpose_body(
    const float* __restrict__ W, unsigned short* __restrict__ WT,
    unsigned short (*tile)[65], int R, int C, int bx, int by, int e, int tid)
{
    const int cb = bx * 64, rb = by * 64;
    const float* src = W + (size_t)e * R * C;
    unsigned short* dst = WT + (size_t)e * R * C;
    const int x = tid & 63, y0 = tid >> 6;
#pragma unroll
    for (int i = 0; i < 16; i++) {
        int r = y0 + i * 4;
        tile[r][x] = f2bf(src[(size_t)(rb + r) * C + cb + x]);
    }
    __syncthreads();
#pragma unroll
    for (int i = 0; i < 16; i++) {
        int c = y0 + i * 4;
        dst[(size_t)(cb + c) * R + rb + x] = tile[x][c];
    }
}

__global__ __launch_bounds__(256) void prep_all(
    const float* __restrict__ X, const float* __restrict__ W1,
    const float* __restrict__ W2, const int* __restrict__ labels,
    unsigned short* __restrict__ Xb, unsigned short* __restrict__ W1T,
    unsigned short* __restrict__ W2T, int* __restrict__ perm)
{
    __shared__ unsigned short tile[64][65];
    const int bid = blockIdx.x;
    const int tid = threadIdx.x;
    if (bid == 0) {
        if (tid < NB) {
            int li = labels[tid];
            int rank = 0;
            for (int j = 0; j < NB; j++) {
                int lj = labels[j];
                if (lj < li || (lj == li && j < tid)) rank++;
            }
            perm[rank] = tid;
        }
        return;
    }
    if (bid <= 2048) {
        const int n8 = NB * SEQ * HID / 8;
        int idx = (bid - 1) * 256 + tid;
        for (int i = idx; i < n8; i += 2048 * 256) {
            f32x4 a = *(const f32x4*)(X + (size_t)i * 8);
            f32x4 b = *(const f32x4*)(X + (size_t)i * 8 + 4);
            unsigned short o[8];
#pragma unroll
            for (int v = 0; v < 4; v++) o[v] = f2bf(a[v]);
#pragma unroll
            for (int v = 0; v < 4; v++) o[4 + v] = f2bf(b[v]);
            *(s16x8*)(Xb + (size_t)i * 8) = *(s16x8*)o;
        }
        return;
    }
    if (bid <= 2048 + 4608) {     // W1 [E][HID][FFN] -> W1T [E][FFN][HID]
        int idx = bid - 2049;
        transpose_body(W1, W1T, tile, HID, FFN, idx % 48, (idx / 48) % 12, idx / 576, tid);
        return;
    }
    {                             // W2 [E][FFN][HID] -> W2T [E][HID][FFN]
        int idx = bid - (2049 + 4608);
        transpose_body(W2, W2T, tile, FFN, HID, idx % 12, (idx / 12) % 48, idx / 576, tid);
    }
}

// ===========================================================================
// gemm1: 512x256 tile, BK=32, 1024 threads (16 waves: 8M x 2N, wave 64x128).
// LDS 96 KB: A bufs @0/32768 (32 KB: 512 rows x 64 B), B bufs @65536/+16384
// (16 KB: 256 rows x 64 B). Swizzle (64-B rows, R8-proven conflict-free):
// byte ^= ((row>>1)&3)<<4, both sides.
// Window w (24 total): 12 ds_read_b128 -> lgkmcnt(0)+barrier -> stage w+2
// into same buf (3 gloads) -> 32 MFMA -> VMCNT(3) [w+1 landed] -> barrier.
// Staged bytes: 384 blocks x 1.15 MB = 442 MB (-25% vs R18's 590 MB).
// ===========================================================================
#define SWZ32(row, cb) ((cb) ^ ((((row) >> 1) & 3) << 4))

__device__ __forceinline__ void stage_A32(const char* g, char* lds, int tid)
{
#pragma unroll
    for (int p = 0; p < 2; p++) {
        int L  = p * 16384 + tid * 16;
        int row = L >> 6;
        int cb  = L & 63;
        GLOAD16(g + (size_t)row * (HID * 2) + SWZ32(row, cb), lds + L);
    }
}
__device__ __forceinline__ void stage_B32(const char* g, char* lds, int tid)
{
    int L  = tid * 16;
    int row = L >> 6;
    int cb  = L & 63;
    GLOAD16(g + (size_t)row * (HID * 2) + SWZ32(row, cb), lds + L);
}

template<bool STG, int VM>
__device__ __forceinline__ void win1(const char* At2, const char* Bt2,
    char* Abuf, char* Bbuf, const int* aoff, const int* boff, int tid,
    f32x4 (&acc)[4][8])
{
    s16x8 a[4], b[8];
#pragma unroll
    for (int mi = 0; mi < 4; mi++) a[mi] = *(const s16x8*)(Abuf + aoff[mi]);
#pragma unroll
    for (int nj = 0; nj < 8; nj++) b[nj] = *(const s16x8*)(Bbuf + boff[nj]);
    asm volatile("s_waitcnt lgkmcnt(0)" ::: "memory");
    __builtin_amdgcn_s_barrier();
    if constexpr (STG) {
        stage_A32(At2, Abuf, tid);
        stage_B32(Bt2, Bbuf, tid);
    }
    __builtin_amdgcn_s_setprio(1);
#pragma unroll
    for (int mi = 0; mi < 4; mi++)
#pragma unroll
        for (int nj = 0; nj < 8; nj++)
            acc[mi][nj] = __builtin_amdgcn_mfma_f32_16x16x32_bf16(
                a[mi], b[nj], acc[mi][nj], 0, 0, 0);
    __builtin_amdgcn_s_setprio(0);
    if constexpr (VM >= 0) VMCNT(VM);
    __builtin_amdgcn_s_barrier();
}

__global__ __launch_bounds__(1024, 1) void moe_gemm1(
    const unsigned short* __restrict__ Xb,
    const int*   __restrict__ labels,
    const int*   __restrict__ perm,
    const unsigned short* __restrict__ W1T,  // [E][FFN][HID]
    const float* __restrict__ B1,
    unsigned short* __restrict__ G)
{
    extern __shared__ char smem[];
    const int L = blockIdx.x;                // 0..383
    const int xcd = L & 7, s = L >> 3;       // s in [0,48)
    const int bs = perm[xcd * 4 + s / 12];
    const int nt = s % 12;
    const int e  = labels[bs];

    const char* Agb = (const char*)(Xb + (size_t)bs * SEQ * HID);
    const char* Bgb = (const char*)(W1T + (size_t)e * FFN * HID + (size_t)nt * 256 * HID);

    const int tid = threadIdx.x;
    const int lane = tid & 63, w = tid >> 6;   // w 0..15
    const int wm = (w >> 1) * 64;              // 0..448
    const int wn = (w & 1) * 128;              // 0 / 128
    const int fr = lane & 15, fq = lane >> 4;

    int aoff[4], boff[8];
#pragma unroll
    for (int mi = 0; mi < 4; mi++) {
        int row = wm + mi * 16 + fr;
        aoff[mi] = row * 64 + SWZ32(row, fq * 16);
    }
#pragma unroll
    for (int nj = 0; nj < 8; nj++) {
        int row = wn + nj * 16 + fr;
        boff[nj] = row * 64 + SWZ32(row, fq * 16);
    }

    char* A0 = smem;
    char* A1 = smem + 32768;
    char* B0 = smem + 65536;
    char* B1s = smem + 65536 + 16384;

    f32x4 acc[4][8];
#pragma unroll
    for (int i = 0; i < 4; i++)
#pragma unroll
        for (int j = 0; j < 8; j++) acc[i][j] = (f32x4)0.0f;

    // prologue: stage w0 -> buf0, w1 -> buf1; wait w0 (oldest 3 of 6)
    stage_A32(Agb,      A0, tid);
    stage_B32(Bgb,      B0, tid);
    stage_A32(Agb + 64, A1, tid);
    stage_B32(Bgb + 64, B1s, tid);
    VMCNT(3);
    __builtin_amdgcn_s_barrier();

    const int KT = HID / 32;   // 24
#pragma unroll 1
    for (int kt = 0; kt < KT - 2; kt += 2) {
        win1<true, 3>(Agb + (size_t)(kt + 2) * 64, Bgb + (size_t)(kt + 2) * 64,
                      A0, B0, aoff, boff, tid, acc);
        win1<true, 3>(Agb + (size_t)(kt + 3) * 64, Bgb + (size_t)(kt + 3) * 64,
                      A1, B1s, aoff, boff, tid, acc);
    }
    win1<false, 0>(nullptr, nullptr, A0, B0, aoff, boff, tid, acc);
    win1<false, -1>(nullptr, nullptr, A1, B1s, aoff, boff, tid, acc);

    asm volatile("s_waitcnt lgkmcnt(0)" ::: "memory");
    __syncthreads();

    // ---- epilogue: 4 quarters of 128 rows; LDS [128][512B] swizzled ----
    const float* b1g = B1 + (size_t)e * FFN + (size_t)nt * 256;
    float bias[8];
#pragma unroll
    for (int nj = 0; nj < 8; nj++) bias[nj] = b1g[wn + nj * 16 + fr];
    char* Cgb = (char*)(G + (size_t)bs * SEQ * FFN + (size_t)nt * 256);

#pragma unroll
    for (int q = 0; q < 4; q++) {
        if ((wm >> 7) == q) {
#pragma unroll
            for (int mi = 0; mi < 4; mi++)
#pragma unroll
                for (int nj = 0; nj < 8; nj++) {
                    const int col = wn + nj * 16 + fr;
#pragma unroll
                    for (int r2 = 0; r2 < 4; r2++) {
                        const int rl = (wm & 127) + mi * 16 + fq * 4 + r2; // 0..127
                        float v = acc[mi][nj][r2] + bias[nj];
                        int byte = rl * 512 + ((col * 2) ^ ((rl & 7) << 4));
                        *(unsigned short*)(smem + byte) = f2bf(gelu_fast(v));
                    }
                }
        }
        __syncthreads();
        // stream 64 KB: 1024 thr x 4 iters x 16 B, full-line NT
#pragma unroll
        for (int it = 0; it < 4; it++) {
            int chunk = tid + it * 1024;      // 0..4095
            int rl = chunk >> 5;              // 0..127
            int cb = (chunk & 31) * 16;
            s16x8 v = *(const s16x8*)(smem + rl * 512 + (cb ^ ((rl & 7) << 4)));
            __builtin_nontemporal_store(v,
                (s16x8*)(Cgb + (size_t)(q * 128 + rl) * (FFN * 2) + cb));
        }
        if (q < 3) __syncthreads();
    }
}

// ---------------------------------------------------------------------------
// gemm2 machinery (R18, unchanged): 256x256 8-phase, BK=64, 8 waves.
// ---------------------------------------------------------------------------
template<int LDB, bool ISA>
__device__ __forceinline__ void stage_region(const char* g, char* lds, int half, int tid)
{
#pragma unroll
    for (int p = 0; p < 2; p++) {
        int L  = p * 8192 + tid * 16;
        int rr = L >> 7;
        int cb = L & 127;
        int row = ISA ? ((rr & 63) + ((rr >> 6) << 7) + half * 64)
                      : ((rr & 31) + ((rr >> 5) << 6) + half * 32);
        int cbs = cb ^ ((row & 7) << 4);
        GLOAD16(g + (size_t)row * LDB + cbs, lds + (size_t)row * 128 + cb);
    }
}

__device__ __forceinline__ void read_af(const char* Ab, int arow_b, int k0, int ih, s16x8 (&a)[2][4])
{
    const int k1 = k0 ^ 64;
#pragma unroll
    for (int i = 0; i < 4; i++) {
        const char* p = Ab + arow_b + (ih * 64 + i * 16) * 128;
        a[0][i] = *(const s16x8*)(p + k0);
        a[1][i] = *(const s16x8*)(p + k1);
    }
}
__device__ __forceinline__ void read_bf(const char* Bb, int brow_b, int k0, int jh, s16x8 (&b)[2][2])
{
    const int k1 = k0 ^ 64;
#pragma unroll
    for (int j = 0; j < 2; j++) {
        const char* p = Bb + brow_b + (jh * 32 + j * 16) * 128;
        b[0][j] = *(const s16x8*)(p + k0);
        b[1][j] = *(const s16x8*)(p + k1);
    }
}

template<int IH, int JH>
__device__ __forceinline__ void mfma_quad(s16x8 (&a)[2][4], s16x8 (&b)[2][2], f32x4 (&acc)[8][4])
{
    __builtin_amdgcn_s_setprio(1);
#pragma unroll
    for (int kk = 0; kk < 2; kk++)
#pragma unroll
        for (int i = 0; i < 4; i++)
#pragma unroll
            for (int j = 0; j < 2; j++)
                acc[IH * 4 + i][JH * 2 + j] = __builtin_amdgcn_mfma_f32_16x16x32_bf16(
                    a[kk][i], b[kk][j], acc[IH * 4 + i][JH * 2 + j], 0, 0, 0);
    __builtin_amdgcn_s_setprio(0);
}

template<int LDB, bool S1, bool S2, int VM>
__device__ __forceinline__ void gwindow(const char* AgK, const char* BgK,
    char* Acur, char* Bcur, char* Anxt, char* Bnxt,
    int arow_b, int brow_b, int k0, int tid, f32x4 (&acc)[8][4])
{
    s16x8 a[2][4], b0[2][2], b1[2][2];
    read_af(Acur, arow_b, k0, 0, a);
    read_bf(Bcur, brow_b, k0, 0, b0);
    if constexpr (S1) stage_region<LDB, true >(AgK + 128, Anxt, 1, tid);
    __builtin_amdgcn_s_barrier();
    mfma_quad<0, 0>(a, b0, acc);
    __builtin_amdgcn_s_barrier();
    read_bf(Bcur, brow_b, k0, 1, b1);
    if constexpr (S1) stage_region<LDB, false>(BgK + 128, Bnxt, 1, tid);
    __builtin_amdgcn_s_barrier();
    mfma_quad<0, 1>(a, b1, acc);
    __builtin_amdgcn_s_barrier();
    read_af(Acur, arow_b, k0, 1, a);
    if constexpr (S2) stage_region<LDB, true >(AgK + 256, Acur, 0, tid);
    __builtin_amdgcn_s_barrier();
    mfma_quad<1, 1>(a, b1, acc);
    __builtin_amdgcn_s_barrier();
    if constexpr (S2) stage_region<LDB, false>(BgK + 256, Bcur, 0, tid);
    __builtin_amdgcn_s_barrier();
    mfma_quad<1, 0>(a, b0, acc);
    if constexpr (VM >= 0) VMCNT(VM);
    __builtin_amdgcn_s_barrier();
}

template<int LDB>
__device__ __forceinline__ void gemm_mainloop(const char* Ag, const char* Bg,
    char* smem, int KT, int tid, int arow_b, int brow_b, int k0, f32x4 (&acc)[8][4])
{
    stage_region<LDB, true >(Ag,       smem,          0, tid);
    stage_region<LDB, false>(Bg,       smem + 65536,  0, tid);
    stage_region<LDB, true >(Ag,       smem,          1, tid);
    stage_region<LDB, false>(Bg,       smem + 65536,  1, tid);
    stage_region<LDB, true >(Ag + 128, smem + 32768,  0, tid);
    stage_region<LDB, false>(Bg + 128, smem + 98304,  0, tid);
    VMCNT(4);
    __builtin_amdgcn_s_barrier();

    int cur = 0;
    for (int kt = 0; kt < KT - 2; ++kt) {
        char* Acur = smem + (cur << 15);
        char* Anxt = smem + ((cur ^ 1) << 15);
        char* Bcur = smem + 65536 + (cur << 15);
        char* Bnxt = smem + 65536 + ((cur ^ 1) << 15);
        gwindow<LDB, true, true, 4>(Ag + (size_t)kt * 128, Bg + (size_t)kt * 128,
            Acur, Bcur, Anxt, Bnxt, arow_b, brow_b, k0, tid, acc);
        cur ^= 1;
    }
    {
        char* Acur = smem + (cur << 15);
        char* Anxt = smem + ((cur ^ 1) << 15);
        char* Bcur = smem + 65536 + (cur << 15);
        char* Bnxt = smem + 65536 + ((cur ^ 1) << 15);
        gwindow<LDB, true, false, 0>(Ag + (size_t)(KT - 2) * 128, Bg + (size_t)(KT - 2) * 128,
            Acur, Bcur, Anxt, Bnxt, arow_b, brow_b, k0, tid, acc);
        cur ^= 1;
    }
    {
        char* Acur = smem + (cur << 15);
        char* Anxt = smem + ((cur ^ 1) << 15);
        char* Bcur = smem + 65536 + (cur << 15);
        char* Bnxt = smem + 65536 + ((cur ^ 1) << 15);
        gwindow<LDB, false, false, -1>(Ag + (size_t)(KT - 1) * 128, Bg + (size_t)(KT - 1) * 128,
            Acur, Bcur, Anxt, Bnxt, arow_b, brow_b, k0, tid, acc);
    }
}

__global__ __launch_bounds__(512, 2) void moe_gemm2(
    const unsigned short* __restrict__ G,
    const int*   __restrict__ labels,
    const int*   __restrict__ perm,
    const unsigned short* __restrict__ W2T,  // [E][HID][FFN]
    const float* __restrict__ B2,
    float* __restrict__ Out)
{
    extern __shared__ char smem[];
    const int L = blockIdx.x;
    const int xcd = L & 7, s = L >> 3;       // s in [0,24)
    const int bs = perm[xcd * 4 + s / 6];
    const int rr = s % 6;
    const int mt = rr / 3, nt = rr % 3;
    const int e  = labels[bs];

    const char* Ag = (const char*)(G + ((size_t)bs * SEQ + (size_t)mt * 256) * FFN);
    const char* Bg = (const char*)(W2T + (size_t)e * HID * FFN + (size_t)nt * 256 * FFN);

    const int tid = threadIdx.x;
    const int lane = tid & 63, w = tid >> 6;
    const int wm = (w >> 2) * 128, wn = (w & 3) * 64;
    const int fr = lane & 15, fq = lane >> 4;
    const int arow_b = (wm + fr) * 128, brow_b = (wn + fr) * 128;
    const int k0 = (fq * 16) ^ ((fr & 7) << 4);

    f32x4 acc[8][4];
#pragma unroll
    for (int i = 0; i < 8; i++)
#pragma unroll
        for (int j = 0; j < 4; j++) acc[i][j] = (f32x4)0.0f;

    gemm_mainloop<FFN * 2>(Ag, Bg, smem, FFN / 64, tid, arow_b, brow_b, k0, acc);

    const float* b2g = B2 + (size_t)e * HID + (size_t)nt * 256;
    float bias[4];
#pragma unroll
    for (int nj = 0; nj < 4; nj++) bias[nj] = b2g[wn + nj * 16 + fr];
    char* Cgb = (char*)(Out + ((size_t)bs * SEQ + (size_t)mt * 256) * HID + (size_t)nt * 256);

#pragma unroll
    for (int half = 0; half < 2; ++half) {
        if ((wn >> 7) == half) {
#pragma unroll
            for (int mi = 0; mi < 8; mi++)
#pragma unroll
                for (int nj = 0; nj < 4; nj++) {
                    const int lcol = (wn & 127) + nj * 16 + fr;   // 0..127
#pragma unroll
                    for (int r2 = 0; r2 < 4; r2++) {
                        const int row = wm + mi * 16 + fq * 4 + r2;
                        int byte = row * 512 + ((lcol * 4) ^ ((row & 7) << 4));
                        *(float*)(smem + byte) = acc[mi][nj][r2] + bias[nj];
                    }
                }
        }
        __syncthreads();
#pragma unroll
        for (int it = 0; it < 16; it++) {
            int chunk = tid + it * 512;
            int row = chunk >> 5;
            int cb  = (chunk & 31) * 16;
            f32x4 v = *(const f32x4*)(smem + row * 512 + (cb ^ ((row & 7) << 4)));
            __builtin_nontemporal_store(v, (f32x4*)(Cgb + (size_t)row * (HID * 4) + half * 512 + cb));
        }
        if (half == 0) __syncthreads();
    }
}

extern "C" void kernel_launch(void* const* d_in, const int* in_sizes, int n_in,
                              void* d_out, int out_size, void* d_ws, size_t ws_size,
                              hipStream_t stream) {
    const float* X      = (const float*)d_in[0];
    const int*   labels = (const int*)  d_in[1];
    const float* W1     = (const float*)d_in[2];
    const float* B1     = (const float*)d_in[3];
    const float* W2     = (const float*)d_in[4];
    const float* B2     = (const float*)d_in[5];
    float* Out = (float*)d_out;

    char* ws = (char*)d_ws;
    unsigned short* Xb  = (unsigned short*)(ws);               // 25,165,824 B
    unsigned short* W1T = (unsigned short*)(ws + 25165824);    // 37,748,736 B
    unsigned short* W2T = (unsigned short*)(ws + 62914560);    // 37,748,736 B
    unsigned short* G   = (unsigned short*)(ws + 100663296);   // 100,663,296 B
    int*            perm = (int*)(ws + 201326592);             // 128 B

    (void)hipFuncSetAttribute((const void*)moe_gemm1,
        hipFuncAttributeMaxDynamicSharedMemorySize, 98304);
    (void)hipFuncSetAttribute((const void*)moe_gemm2,
        hipFuncAttributeMaxDynamicSharedMemorySize, 131072);

    // single merged prep: sort(1) + cvt_x(2048) + W1T(4608) + W2T(4608)
    prep_all<<<1 + 2048 + 4608 + 4608, 256, 0, stream>>>(
        X, W1, W2, labels, Xb, W1T, W2T, perm);

    moe_gemm1<<<384, dim3(1024), 98304, stream>>>(Xb, labels, perm, W1T, B1, G);
    moe_gemm2<<<192, dim3(512), 131072, stream>>>(G, labels, perm, W2T, B2, Out);
}

// Round 20
// 226.587 us; speedup vs baseline: 6.0122x; 6.0122x over previous
//
#include <hip/hip_runtime.h>
#include <hip/hip_bf16.h>

#define NB   32
#define SEQ  512
#define HID  768
#define FFN  3072
#define NEXP 8

typedef float f32x4 __attribute__((ext_vector_type(4)));
typedef short s16x8 __attribute__((ext_vector_type(8)));

__device__ __forceinline__ unsigned short f2bf(float f) {
    return __builtin_bit_cast(unsigned short, (__bf16)f);
}

__device__ __forceinline__ float fast_exp2(float x) {
    float r; asm("v_exp_f32 %0, %1" : "=v"(r) : "v"(x)); return r;
}
__device__ __forceinline__ float fast_rcp(float x) {
    float r; asm("v_rcp_f32 %0, %1" : "=v"(r) : "v"(x)); return r;
}

// tanh-gelu, overflow-free (exp2 arg <= 0). |error| vs exact-erf gelu ~2e-4.
__device__ __forceinline__ float gelu_fast(float v) {
    float u  = v * (0.7978845608f + 0.0356774081f * v * v);
    float t  = fast_exp2(-2.8853900817779268f * fabsf(u));
    float T  = (1.0f - t) * fast_rcp(1.0f + t);
    return 0.5f * v + 0.5f * fabsf(v) * T;
}

#define GLOAD16(gp, lp) __builtin_amdgcn_global_load_lds( \
    (const __attribute__((address_space(1))) unsigned int*)(gp), \
    (__attribute__((address_space(3))) unsigned int*)(lp), 16, 0, 0)

#define VMCNT(N) asm volatile("s_waitcnt vmcnt(%0)" :: "i"(N) : "memory")

// ---------------------------------------------------------------------------
// Merged prep (single launch): block 0 = label sort; 1..2048 = X fp32->bf16;
// 2049..6656 = W1 transpose; 6657..11264 = W2 transpose. All plain layouts.
// ---------------------------------------------------------------------------
__device__ __forceinline__ void transpose_body(
    const float* __restrict__ W, unsigned short* __restrict__ WT,
    unsigned short (*tile)[65], int R, int C, int bx, int by, int e, int tid)
{
    const int cb = bx * 64, rb = by * 64;
    const float* src = W + (size_t)e * R * C;
    unsigned short* dst = WT + (size_t)e * R * C;
    const int x = tid & 63, y0 = tid >> 6;
#pragma unroll
    for (int i = 0; i < 16; i++) {
        int r = y0 + i * 4;
        tile[r][x] = f2bf(src[(size_t)(rb + r) * C + cb + x]);
    }
    __syncthreads();
#pragma unroll
    for (int i = 0; i < 16; i++) {
        int c = y0 + i * 4;
        dst[(size_t)(cb + c) * R + rb + x] = tile[x][c];
    }
}

__global__ __launch_bounds__(256) void prep_all(
    const float* __restrict__ X, const float* __restrict__ W1,
    const float* __restrict__ W2, const int* __restrict__ labels,
    unsigned short* __restrict__ Xb, unsigned short* __restrict__ W1T,
    unsigned short* __restrict__ W2T, int* __restrict__ perm)
{
    __shared__ unsigned short tile[64][65];
    const int bid = blockIdx.x;
    const int tid = threadIdx.x;
    if (bid == 0) {
        if (tid < NB) {
            int li = labels[tid];
            int rank = 0;
            for (int j = 0; j < NB; j++) {
                int lj = labels[j];
                if (lj < li || (lj == li && j < tid)) rank++;
            }
            perm[rank] = tid;
        }
        return;
    }
    if (bid <= 2048) {
        const int n8 = NB * SEQ * HID / 8;
        int idx = (bid - 1) * 256 + tid;
        for (int i = idx; i < n8; i += 2048 * 256) {
            f32x4 a = *(const f32x4*)(X + (size_t)i * 8);
            f32x4 b = *(const f32x4*)(X + (size_t)i * 8 + 4);
            unsigned short o[8];
#pragma unroll
            for (int v = 0; v < 4; v++) o[v] = f2bf(a[v]);
#pragma unroll
            for (int v = 0; v < 4; v++) o[4 + v] = f2bf(b[v]);
            *(s16x8*)(Xb + (size_t)i * 8) = *(s16x8*)o;
        }
        return;
    }
    if (bid <= 2048 + 4608) {     // W1 [E][HID][FFN] -> W1T [E][FFN][HID]
        int idx = bid - 2049;
        transpose_body(W1, W1T, tile, HID, FFN, idx % 48, (idx / 48) % 12, idx / 576, tid);
        return;
    }
    {                             // W2 [E][FFN][HID] -> W2T [E][HID][FFN]
        int idx = bid - (2049 + 4608);
        transpose_body(W2, W2T, tile, FFN, HID, idx % 12, (idx / 12) % 48, idx / 576, tid);
    }
}

// ---------------------------------------------------------------------------
// 256x256 8-phase GEMM window machinery (BK=64, 8 waves, 2 x 64KB LDS bufs)
// ---------------------------------------------------------------------------
template<int LDB, bool ISA>
__device__ __forceinline__ void stage_region(const char* g, char* lds, int half, int tid)
{
#pragma unroll
    for (int p = 0; p < 2; p++) {
        int L  = p * 8192 + tid * 16;
        int rr = L >> 7;
        int cb = L & 127;
        int row = ISA ? ((rr & 63) + ((rr >> 6) << 7) + half * 64)
                      : ((rr & 31) + ((rr >> 5) << 6) + half * 32);
        int cbs = cb ^ ((row & 7) << 4);
        GLOAD16(g + (size_t)row * LDB + cbs, lds + (size_t)row * 128 + cb);
    }
}

__device__ __forceinline__ void read_af(const char* Ab, int arow_b, int k0, int ih, s16x8 (&a)[2][4])
{
    const int k1 = k0 ^ 64;
#pragma unroll
    for (int i = 0; i < 4; i++) {
        const char* p = Ab + arow_b + (ih * 64 + i * 16) * 128;
        a[0][i] = *(const s16x8*)(p + k0);
        a[1][i] = *(const s16x8*)(p + k1);
    }
}
__device__ __forceinline__ void read_bf(const char* Bb, int brow_b, int k0, int jh, s16x8 (&b)[2][2])
{
    const int k1 = k0 ^ 64;
#pragma unroll
    for (int j = 0; j < 2; j++) {
        const char* p = Bb + brow_b + (jh * 32 + j * 16) * 128;
        b[0][j] = *(const s16x8*)(p + k0);
        b[1][j] = *(const s16x8*)(p + k1);
    }
}

template<int IH, int JH>
__device__ __forceinline__ void mfma_quad(s16x8 (&a)[2][4], s16x8 (&b)[2][2], f32x4 (&acc)[8][4])
{
    __builtin_amdgcn_s_setprio(1);
#pragma unroll
    for (int kk = 0; kk < 2; kk++)
#pragma unroll
        for (int i = 0; i < 4; i++)
#pragma unroll
            for (int j = 0; j < 2; j++)
                acc[IH * 4 + i][JH * 2 + j] = __builtin_amdgcn_mfma_f32_16x16x32_bf16(
                    a[kk][i], b[kk][j], acc[IH * 4 + i][JH * 2 + j], 0, 0, 0);
    __builtin_amdgcn_s_setprio(0);
}

template<int LDB, bool S1, bool S2, int VM>
__device__ __forceinline__ void gwindow(const char* AgK, const char* BgK,
    char* Acur, char* Bcur, char* Anxt, char* Bnxt,
    int arow_b, int brow_b, int k0, int tid, f32x4 (&acc)[8][4])
{
    s16x8 a[2][4], b0[2][2], b1[2][2];
    read_af(Acur, arow_b, k0, 0, a);
    read_bf(Bcur, brow_b, k0, 0, b0);
    if constexpr (S1) stage_region<LDB, true >(AgK + 128, Anxt, 1, tid);
    __builtin_amdgcn_s_barrier();
    mfma_quad<0, 0>(a, b0, acc);
    __builtin_amdgcn_s_barrier();
    read_bf(Bcur, brow_b, k0, 1, b1);
    if constexpr (S1) stage_region<LDB, false>(BgK + 128, Bnxt, 1, tid);
    __builtin_amdgcn_s_barrier();
    mfma_quad<0, 1>(a, b1, acc);
    __builtin_amdgcn_s_barrier();
    read_af(Acur, arow_b, k0, 1, a);
    if constexpr (S2) stage_region<LDB, true >(AgK + 256, Acur, 0, tid);
    __builtin_amdgcn_s_barrier();
    mfma_quad<1, 1>(a, b1, acc);
    __builtin_amdgcn_s_barrier();
    if constexpr (S2) stage_region<LDB, false>(BgK + 256, Bcur, 0, tid);
    __builtin_amdgcn_s_barrier();
    mfma_quad<1, 0>(a, b0, acc);
    if constexpr (VM >= 0) VMCNT(VM);
    __builtin_amdgcn_s_barrier();
}

template<int LDB>
__device__ __forceinline__ void gemm_mainloop(const char* Ag, const char* Bg,
    char* smem, int KT, int tid, int arow_b, int brow_b, int k0, f32x4 (&acc)[8][4])
{
    stage_region<LDB, true >(Ag,       smem,          0, tid);
    stage_region<LDB, false>(Bg,       smem + 65536,  0, tid);
    stage_region<LDB, true >(Ag,       smem,          1, tid);
    stage_region<LDB, false>(Bg,       smem + 65536,  1, tid);
    stage_region<LDB, true >(Ag + 128, smem + 32768,  0, tid);
    stage_region<LDB, false>(Bg + 128, smem + 98304,  0, tid);
    VMCNT(4);
    __builtin_amdgcn_s_barrier();

    int cur = 0;
    for (int kt = 0; kt < KT - 2; ++kt) {
        char* Acur = smem + (cur << 15);
        char* Anxt = smem + ((cur ^ 1) << 15);
        char* Bcur = smem + 65536 + (cur << 15);
        char* Bnxt = smem + 65536 + ((cur ^ 1) << 15);
        gwindow<LDB, true, true, 4>(Ag + (size_t)kt * 128, Bg + (size_t)kt * 128,
            Acur, Bcur, Anxt, Bnxt, arow_b, brow_b, k0, tid, acc);
        cur ^= 1;
    }
    {
        char* Acur = smem + (cur << 15);
        char* Anxt = smem + ((cur ^ 1) << 15);
        char* Bcur = smem + 65536 + (cur << 15);
        char* Bnxt = smem + 65536 + ((cur ^ 1) << 15);
        gwindow<LDB, true, false, 0>(Ag + (size_t)(KT - 2) * 128, Bg + (size_t)(KT - 2) * 128,
            Acur, Bcur, Anxt, Bnxt, arow_b, brow_b, k0, tid, acc);
        cur ^= 1;
    }
    {
        char* Acur = smem + (cur << 15);
        char* Anxt = smem + ((cur ^ 1) << 15);
        char* Bcur = smem + 65536 + (cur << 15);
        char* Bnxt = smem + 65536 + ((cur ^ 1) << 15);
        gwindow<LDB, false, false, -1>(Ag + (size_t)(KT - 1) * 128, Bg + (size_t)(KT - 1) * 128,
            Acur, Bcur, Anxt, Bnxt, arow_b, brow_b, k0, tid, acc);
    }
}

// ---------------------------------------------------------------------------
// Kernel 1: G = gelu(Xb @ W1[e] + b1[e]) -> bf16 (best-measured variant)
// ---------------------------------------------------------------------------
__global__ __launch_bounds__(512, 2) void moe_gemm1(
    const unsigned short* __restrict__ Xb,
    const int*   __restrict__ labels,
    const int*   __restrict__ perm,
    const unsigned short* __restrict__ W1T,  // [E][FFN][HID]
    const float* __restrict__ B1,
    unsigned short* __restrict__ G)
{
    extern __shared__ char smem[];
    const int L = blockIdx.x;
    const int xcd  = L & 7;
    const int r    = L >> 8;          // band 0..2
    const int i    = (L >> 3) & 31;
    const int pair = i >> 2;          // 0..7
    const int bs = perm[xcd * 4 + (pair >> 1)];
    const int mt = pair & 1;
    const int nt = r * 4 + (i & 3);
    const int e  = labels[bs];

    const char* Ag = (const char*)(Xb + ((size_t)bs * SEQ + (size_t)mt * 256) * HID);
    const char* Bg = (const char*)(W1T + (size_t)e * FFN * HID + (size_t)nt * 256 * HID);

    const int tid = threadIdx.x;
    const int lane = tid & 63, w = tid >> 6;
    const int wm = (w >> 2) * 128, wn = (w & 3) * 64;
    const int fr = lane & 15, fq = lane >> 4;
    const int arow_b = (wm + fr) * 128, brow_b = (wn + fr) * 128;
    const int k0 = (fq * 16) ^ ((fr & 7) << 4);

    f32x4 acc[8][4];
#pragma unroll
    for (int i2 = 0; i2 < 8; i2++)
#pragma unroll
        for (int j = 0; j < 4; j++) acc[i2][j] = (f32x4)0.0f;

    gemm_mainloop<HID * 2>(Ag, Bg, smem, HID / 64, tid, arow_b, brow_b, k0, acc);

    // ---- epilogue: bias+gelu -> LDS bf16 tile [256][256] (XOR-swizzled) ----
    const float* b1g = B1 + (size_t)e * FFN + (size_t)nt * 256;
    float bias[4];
#pragma unroll
    for (int nj = 0; nj < 4; nj++) bias[nj] = b1g[wn + nj * 16 + fr];
#pragma unroll
    for (int mi = 0; mi < 8; mi++)
#pragma unroll
        for (int nj = 0; nj < 4; nj++) {
            const int col = wn + nj * 16 + fr;
#pragma unroll
            for (int r2 = 0; r2 < 4; r2++) {
                const int row = wm + mi * 16 + fq * 4 + r2;
                float v = acc[mi][nj][r2] + bias[nj];
                int byte = row * 512 + ((col * 2) ^ ((row & 7) << 4));
                *(unsigned short*)(smem + byte) = f2bf(gelu_fast(v));
            }
        }
    __syncthreads();
    // ---- stream out: 16B/lane fully-coalesced nontemporal (full lines) ----
    char* Cgb = (char*)(G + ((size_t)bs * SEQ + (size_t)mt * 256) * FFN + (size_t)nt * 256);
#pragma unroll
    for (int it = 0; it < 16; it++) {
        int chunk = tid + it * 512;       // 0..8191
        int row = chunk >> 5;
        int cb  = (chunk & 31) * 16;
        s16x8 v = *(const s16x8*)(smem + row * 512 + (cb ^ ((row & 7) << 4)));
        __builtin_nontemporal_store(v, (s16x8*)(Cgb + (size_t)row * (FFN * 2) + cb));
    }
}

// ---------------------------------------------------------------------------
// Kernel 2: Out = G @ W2[e] + b2[e] -> fp32; LDS-coalesced NT epilogue.
// ---------------------------------------------------------------------------
__global__ __launch_bounds__(512, 2) void moe_gemm2(
    const unsigned short* __restrict__ G,
    const int*   __restrict__ labels,
    const int*   __restrict__ perm,
    const unsigned short* __restrict__ W2T,  // [E][HID][FFN]
    const float* __restrict__ B2,
    float* __restrict__ Out)
{
    extern __shared__ char smem[];
    const int L = blockIdx.x;
    const int xcd = L & 7, s = L >> 3;       // s in [0,24)
    const int bs = perm[xcd * 4 + s / 6];
    const int rr = s % 6;
    const int mt = rr / 3, nt = rr % 3;
    const int e  = labels[bs];

    const char* Ag = (const char*)(G + ((size_t)bs * SEQ + (size_t)mt * 256) * FFN);
    const char* Bg = (const char*)(W2T + (size_t)e * HID * FFN + (size_t)nt * 256 * FFN);

    const int tid = threadIdx.x;
    const int lane = tid & 63, w = tid >> 6;
    const int wm = (w >> 2) * 128, wn = (w & 3) * 64;
    const int fr = lane & 15, fq = lane >> 4;
    const int arow_b = (wm + fr) * 128, brow_b = (wn + fr) * 128;
    const int k0 = (fq * 16) ^ ((fr & 7) << 4);

    f32x4 acc[8][4];
#pragma unroll
    for (int i = 0; i < 8; i++)
#pragma unroll
        for (int j = 0; j < 4; j++) acc[i][j] = (f32x4)0.0f;

    gemm_mainloop<FFN * 2>(Ag, Bg, smem, FFN / 64, tid, arow_b, brow_b, k0, acc);

    const float* b2g = B2 + (size_t)e * HID + (size_t)nt * 256;
    float bias[4];
#pragma unroll
    for (int nj = 0; nj < 4; nj++) bias[nj] = b2g[wn + nj * 16 + fr];
    char* Cgb = (char*)(Out + ((size_t)bs * SEQ + (size_t)mt * 256) * HID + (size_t)nt * 256);

#pragma unroll
    for (int half = 0; half < 2; ++half) {
        if ((wn >> 7) == half) {
#pragma unroll
            for (int mi = 0; mi < 8; mi++)
#pragma unroll
                for (int nj = 0; nj < 4; nj++) {
                    const int lcol = (wn & 127) + nj * 16 + fr;   // 0..127
#pragma unroll
                    for (int r2 = 0; r2 < 4; r2++) {
                        const int row = wm + mi * 16 + fq * 4 + r2;
                        int byte = row * 512 + ((lcol * 4) ^ ((row & 7) << 4));
                        *(float*)(smem + byte) = acc[mi][nj][r2] + bias[nj];
                    }
                }
        }
        __syncthreads();
#pragma unroll
        for (int it = 0; it < 16; it++) {
            int chunk = tid + it * 512;
            int row = chunk >> 5;
            int cb  = (chunk & 31) * 16;
            f32x4 v = *(const f32x4*)(smem + row * 512 + (cb ^ ((row & 7) << 4)));
            __builtin_nontemporal_store(v, (f32x4*)(Cgb + (size_t)row * (HID * 4) + half * 512 + cb));
        }
        if (half == 0) __syncthreads();
    }
}

extern "C" void kernel_launch(void* const* d_in, const int* in_sizes, int n_in,
                              void* d_out, int out_size, void* d_ws, size_t ws_size,
                              hipStream_t stream) {
    const float* X      = (const float*)d_in[0];
    const int*   labels = (const int*)  d_in[1];
    const float* W1     = (const float*)d_in[2];
    const float* B1     = (const float*)d_in[3];
    const float* W2     = (const float*)d_in[4];
    const float* B2     = (const float*)d_in[5];
    float* Out = (float*)d_out;

    char* ws = (char*)d_ws;
    unsigned short* Xb  = (unsigned short*)(ws);               // 25,165,824 B
    unsigned short* W1T = (unsigned short*)(ws + 25165824);    // 37,748,736 B
    unsigned short* W2T = (unsigned short*)(ws + 62914560);    // 37,748,736 B
    unsigned short* G   = (unsigned short*)(ws + 100663296);   // 100,663,296 B
    int*            perm = (int*)(ws + 201326592);             // 128 B

    (void)hipFuncSetAttribute((const void*)moe_gemm1,
        hipFuncAttributeMaxDynamicSharedMemorySize, 131072);
    (void)hipFuncSetAttribute((const void*)moe_gemm2,
        hipFuncAttributeMaxDynamicSharedMemorySize, 131072);

    // single merged prep: sort(1) + cvt_x(2048) + W1T(4608) + W2T(4608)
    prep_all<<<1 + 2048 + 4608 + 4608, 256, 0, stream>>>(
        X, W1, W2, labels, Xb, W1T, W2T, perm);

    moe_gemm1<<<768, dim3(512), 131072, stream>>>(Xb, labels, perm, W1T, B1, G);
    moe_gemm2<<<192, dim3(512), 131072, stream>>>(G, labels, perm, W2T, B2, Out);
}